// Round 4
// baseline (1074.812 us; speedup 1.0000x reference)
//
#include <hip/hip_runtime.h>

// CWTConv2D: x (32,512,512) f32 -> round; k (32,3,3) -> round+clip to {-1,0,1},
// spatially flipped conv (VALID) -> out (32,510,510,32) NHWC f32, +round(bias), relu.
//
// R8: multi-row blocking — the one axis not yet varied (R4/R6/R7 all ~1060 us).
// One block = 8 output rows of one batch image. Grid 64x32 = 2048 blocks
// (exactly 8 per CU). LDS stages 10 input rows (20 KB) ONCE; weight quant
// amortized 8x; global x traffic drops 3x -> 1.25x; each block emits a long
// 512 KB store stream after a single syncthreads (fill-like wave behavior).
// Discriminator: if neutral again, conv is at its write roofline and dur_us
// is dominated by the harness's fixed 4.26 GB re-poison fill (~685 us).

#define BATCH 32
#define H 512
#define W 512
#define NF 32
#define HO 510
#define WO 510
#define RPB 8            // output rows per block
#define NRG ((HO + RPB - 1) / RPB)   // 64 row groups

typedef float vfloat4 __attribute__((ext_vector_type(4)));

__global__ __launch_bounds__(256) void cwt_conv_kernel(
    const float* __restrict__ x,
    const float* __restrict__ kw,
    const float* __restrict__ bias,
    float* __restrict__ out)
{
    __shared__ float xs[RPB + 2][W];   // 20 KB: quantized input rows i0..i0+9
    __shared__ float ws[9][NF];        // quantized, spatially-flipped weights [tap][filter]
    __shared__ float bs[NF];           // rounded biases

    const int tid = threadIdx.x;
    const int ig  = blockIdx.x;        // row group 0..63
    const int b   = blockIdx.y;
    const int i0  = ig * RPB;          // first output row of this block

    // --- Stage quantized weights: tap t=(di*3+dj) uses kw[f][2-di][2-dj] = kw[f*9 + 8-t].
    for (int idx = tid; idx < 9 * NF; idx += 256) {
        const int t = idx >> 5;        // tap 0..8
        const int f = idx & 31;        // filter 0..31
        const float v = rintf(kw[f * 9 + (8 - t)]);
        ws[t][f] = fminf(fmaxf(v, -1.0f), 1.0f);
    }
    if (tid < NF) bs[tid] = rintf(bias[tid]);

    // --- Stage x rows i0 .. i0+nrows-1, rounded once (coalesced float4 loads).
    const int nrows = (H - i0 < RPB + 2) ? (H - i0) : (RPB + 2);  // 10, or 8 for last group
    const int nunits = nrows * (W / 4);                           // float4 units to stage
#pragma unroll
    for (int k = 0; k < 5; ++k) {                                 // 5*256 = 1280 >= 1280 max
        const int idx = tid + k * 256;
        if (idx < nunits) {
            const int r  = idx >> 7;          // staged row 0..nrows-1
            const int c4 = idx & 127;         // float4 col
            const float4 v =
                reinterpret_cast<const float4*>(x + ((size_t)(b * H + i0 + r)) * W)[c4];
            float* d = &xs[r][c4 * 4];
            d[0] = rintf(v.x); d[1] = rintf(v.y);
            d[2] = rintf(v.z); d[3] = rintf(v.w);
        }
    }
    __syncthreads();

    // --- Lane map: f4 fastest so wave stores are address-contiguous (1 KB bursts).
    const int lane = tid & 63;
    const int wv   = tid >> 6;     // wave 0..3: j block [128*wv, 128*wv+127]
    const int f4   = lane & 7;     // filter quad: filters 4*f4..4*f4+3
    const int jg   = lane >> 3;    // 0..7

    float wq[9][4];
#pragma unroll
    for (int t = 0; t < 9; ++t) {
        const float4 w4 = *reinterpret_cast<const float4*>(&ws[t][f4 * 4]);
        wq[t][0] = w4.x; wq[t][1] = w4.y; wq[t][2] = w4.z; wq[t][3] = w4.w;
    }
    float bq[4];
    {
        const float4 b4 = *reinterpret_cast<const float4*>(&bs[f4 * 4]);
        bq[0] = b4.x; bq[1] = b4.y; bq[2] = b4.z; bq[3] = b4.w;
    }

    const int jbase = wv * 128 + jg;
    vfloat4* out4 = reinterpret_cast<vfloat4*>(out);

    for (int rr = 0; rr < RPB; ++rr) {
        const int i = i0 + rr;
        if (i >= HO) break;            // last group: 6 valid rows
        const int obase = ((b * HO + i) * WO + jbase) * (NF / 4) + f4;

#pragma unroll 4
        for (int s = 0; s < 16; ++s) {
            const int j = jbase + 8 * s;        // mask j=510/511 (s==15, jg>=6)
            if (j < WO) {
                float a0 = bq[0], a1 = bq[1], a2 = bq[2], a3 = bq[3];
#pragma unroll
                for (int r = 0; r < 3; ++r) {
#pragma unroll
                    for (int dj = 0; dj < 3; ++dj) {
                        const float xv = xs[rr + r][j + dj];   // 8-way broadcast, conflict-free
                        const int t = r * 3 + dj;
                        a0 = fmaf(xv, wq[t][0], a0);
                        a1 = fmaf(xv, wq[t][1], a1);
                        a2 = fmaf(xv, wq[t][2], a2);
                        a3 = fmaf(xv, wq[t][3], a3);
                    }
                }
                vfloat4 o;
                o.x = fmaxf(a0, 0.0f);
                o.y = fmaxf(a1, 0.0f);
                o.z = fmaxf(a2, 0.0f);
                o.w = fmaxf(a3, 0.0f);
                out4[obase + s * 8 * (NF / 4)] = o;
            }
        }
    }
}

extern "C" void kernel_launch(void* const* d_in, const int* in_sizes, int n_in,
                              void* d_out, int out_size, void* d_ws, size_t ws_size,
                              hipStream_t stream) {
    const float* x    = (const float*)d_in[0];
    const float* kw   = (const float*)d_in[1];
    const float* bias = (const float*)d_in[2];
    float* out = (float*)d_out;

    dim3 grid(NRG, BATCH);   // 64 x 32 = 2048 blocks, 8 output rows each
    dim3 block(256);
    cwt_conv_kernel<<<grid, block, 0, stream>>>(x, kw, bias, out);
}